// Round 1
// baseline (711.376 us; speedup 1.0000x reference)
//
#include <hip/hip_runtime.h>
#include <hip/hip_bf16.h>
#include <math.h>

// Problem constants (B=4, N=2048, D=1024, E=8, H=4096, C = int(2048*1.25//8)=320)
#define B_ 4
#define N_ 2048
#define D_ 1024
#define E_ 8
#define H_ 4096
#define C_ 320
#define M_ (B_*C_)        // 1280 rows per expert in the grouped GEMMs

typedef __attribute__((ext_vector_type(8))) short short8;   // 8 bf16 = 4 VGPRs (MFMA A/B frag)
typedef __attribute__((ext_vector_type(4))) float floatx4;  // MFMA C/D frag

__device__ __forceinline__ unsigned short f2bf(float f) {
  unsigned u = __builtin_bit_cast(unsigned, f);
  u += 0x7fffu + ((u >> 16) & 1u);          // RNE; inputs are tame (no NaN/Inf)
  return (unsigned short)(u >> 16);
}

__device__ __forceinline__ float gelu_tanh(float x) {
  // jax.nn.gelu default (approximate=True)
  return 0.5f * x * (1.f + tanhf(0.7978845608028654f * (x + 0.044715f * x * x * x)));
}

// ---------------------------------------------------------------------------
// K1: router. One wave per token. fp64 dot accumulation to minimize argmax
// flips vs the numpy fp32 reference. Block covers 4 tokens of the same batch b.
// stats layout (fp32): [0..31]=count[b*8+e], [32..63]=proxy[b*8+e], [64]=sum z^2
// ---------------------------------------------------------------------------
__global__ __launch_bounds__(256) void router_kernel(
    const float* __restrict__ x, const float* __restrict__ wr,
    int* __restrict__ idx_buf, float* __restrict__ gate_buf,
    float* __restrict__ stats)
{
  int lane  = threadIdx.x & 63;
  int wave  = threadIdx.x >> 6;
  int token = blockIdx.x * 4 + wave;        // 0..8191
  int b     = token >> 11;                  // N_=2048

  const float* xp = x + (size_t)token * D_ + lane * 16;
  float xv[16];
#pragma unroll
  for (int i = 0; i < 4; i++) {
    float4 v = ((const float4*)xp)[i];
    xv[i*4+0]=v.x; xv[i*4+1]=v.y; xv[i*4+2]=v.z; xv[i*4+3]=v.w;
  }
  double acc[8];
#pragma unroll
  for (int e = 0; e < 8; e++) acc[e] = 0.0;
  const float* wp = wr + (size_t)(lane * 16) * E_;   // w_router is [D][E]
#pragma unroll
  for (int i = 0; i < 16; i++) {
    float xs = xv[i];
#pragma unroll
    for (int e = 0; e < 8; e++) acc[e] += (double)xs * (double)wp[i*8 + e];
  }
  for (int off = 32; off > 0; off >>= 1) {
#pragma unroll
    for (int e = 0; e < 8; e++) acc[e] += __shfl_xor(acc[e], off, 64);
  }

  float l[8];
#pragma unroll
  for (int e = 0; e < 8; e++) l[e] = (float)acc[e];
  float m = l[0]; int best = 0;
#pragma unroll
  for (int e = 1; e < 8; e++) if (l[e] > m) { m = l[e]; best = e; }   // first-max tiebreak
  float p[8], sum = 0.f;
#pragma unroll
  for (int e = 0; e < 8; e++) { p[e] = expf(l[e] - m); sum += p[e]; }
  float inv = 1.f / sum;
#pragma unroll
  for (int e = 0; e < 8; e++) p[e] *= inv;
  float z    = m + logf(sum);
  float gate = inv;                      // softmax at argmax = exp(0)/sum

  __shared__ float s_cnt[8], s_prox[8], s_zsq[1];
  if (threadIdx.x < 8)  { s_cnt[threadIdx.x] = 0.f; s_prox[threadIdx.x] = 0.f; }
  if (threadIdx.x == 8) s_zsq[0] = 0.f;
  __syncthreads();
  if (lane == 0) {
    idx_buf[token]  = best;
    gate_buf[token] = gate;
    atomicAdd(&s_zsq[0], z * z);
    atomicAdd(&s_cnt[best], 1.f);
#pragma unroll
    for (int e = 0; e < 8; e++) atomicAdd(&s_prox[e], p[e]);
  }
  __syncthreads();
  if (threadIdx.x < 8) {
    atomicAdd(&stats[b*8 + threadIdx.x],      s_cnt[threadIdx.x]);
    atomicAdd(&stats[32 + b*8 + threadIdx.x], s_prox[threadIdx.x]);
  }
  if (threadIdx.x == 8) atomicAdd(&stats[64], s_zsq[0]);
}

// ---------------------------------------------------------------------------
// K2: per-(b,e) capacity scan. One wave per (b,e); ballot prefix-sum over N.
// slot_token[(e*B+b)*C + c] = global token id, or -1 (pre-memset) if unused.
// ---------------------------------------------------------------------------
__global__ __launch_bounds__(64) void pos_kernel(
    const int* __restrict__ idx_buf, int* __restrict__ slot_token)
{
  int be = blockIdx.x;                 // 0..31
  int b = be >> 3, e = be & 7;
  int lane = threadIdx.x;
  int base = 0;
  int* out = slot_token + (size_t)(e * B_ + b) * C_;
  for (int n0 = 0; n0 < N_; n0 += 64) {
    int n = n0 + lane;
    bool match = (idx_buf[b * N_ + n] == e);
    unsigned long long mask = __ballot(match);
    int my = base + __popcll(mask & ((1ull << lane) - 1ull));
    if (match && my < C_) out[my] = b * N_ + n;
    base += __popcll(mask);
  }
}

// ---------------------------------------------------------------------------
// K3: gather+cast x rows into xe bf16 [E][M_][D]. One block per slot row.
// ---------------------------------------------------------------------------
__global__ __launch_bounds__(256) void gather_kernel(
    const float* __restrict__ x, const int* __restrict__ slot_token,
    unsigned short* __restrict__ xe)
{
  int row = blockIdx.x;                // 0..E*M_-1  == (e*B+b)*C + c
  int t = slot_token[row];
  int col = threadIdx.x * 4;
  ushort4 o;
  if (t >= 0) {
    float4 v = *(const float4*)(x + (size_t)t * D_ + col);
    o.x = f2bf(v.x); o.y = f2bf(v.y); o.z = f2bf(v.z); o.w = f2bf(v.w);
  } else {
    o.x = 0; o.y = 0; o.z = 0; o.w = 0;
  }
  *(ushort4*)(xe + (size_t)row * D_ + col) = o;
}

// ---------------------------------------------------------------------------
// K4: transpose+cast weights: in fp32 [E][R][Cc] -> out bf16 [E][Cc][R]
// (B^T layout: GEMM B-fragments become k-contiguous ds_read_b128).
// ---------------------------------------------------------------------------
__global__ __launch_bounds__(256) void transcast_kernel(
    const float* __restrict__ in, unsigned short* __restrict__ out, int R, int Cc)
{
  int e = blockIdx.z;
  const float* pin = in + (size_t)e * R * Cc;
  unsigned short* pout = out + (size_t)e * R * Cc;
  __shared__ float T[32][33];
  int r0 = blockIdx.y * 32, c0 = blockIdx.x * 32;
  {
    int lr = threadIdx.x >> 3, lc4 = (threadIdx.x & 7) * 4;
    float4 v = *(const float4*)(pin + (size_t)(r0 + lr) * Cc + c0 + lc4);
    T[lr][lc4+0] = v.x; T[lr][lc4+1] = v.y; T[lr][lc4+2] = v.z; T[lr][lc4+3] = v.w;
  }
  __syncthreads();
  {
    int oc = threadIdx.x >> 3, or4 = (threadIdx.x & 7) * 4;
    ushort4 o;
    o.x = f2bf(T[or4+0][oc]); o.y = f2bf(T[or4+1][oc]);
    o.z = f2bf(T[or4+2][oc]); o.w = f2bf(T[or4+3][oc]);
    *(ushort4*)(pout + (size_t)(c0 + oc) * R + r0 + or4) = o;
  }
}

// ---------------------------------------------------------------------------
// K5: grouped GEMM, m93 pattern. C_tile = A[e] (row-major, k-contig) x BT[e]^T.
// BM=BN=128, BK=32; 4 waves each 64x64 via 4x4 mfma_f32_16x16x32_bf16.
// LDS rows padded to 40 bf16 (80 B, 16B-aligned) -> frag ds_read_b128 is
// 2-way bank aliased = free (m136).
// EPI=0: h = gelu(acc + b1)  -> bf16 Hout [E][M][Nn]
// EPI=1: out[token][col] = gate * (acc + b2), scattered via slot_token
// ---------------------------------------------------------------------------
template<int EPI>
__global__ __launch_bounds__(256) void gemm_kernel(
    const unsigned short* __restrict__ A,    // [E][M][K] bf16
    const unsigned short* __restrict__ BT,   // [E][Nn][K] bf16
    const float* __restrict__ bias,          // [E][Nn] fp32
    unsigned short* __restrict__ Hout,       // EPI=0
    float* __restrict__ Out,                 // EPI=1 (pre-zeroed d_out)
    const int* __restrict__ slot_token,      // EPI=1
    const float* __restrict__ gate_buf,      // EPI=1
    int M, int K, int Nn)
{
  int e  = blockIdx.z;
  int m0 = blockIdx.y * 128;
  int n0 = blockIdx.x * 128;
  const unsigned short* Ae = A  + (size_t)e * M  * K;
  const unsigned short* Be = BT + (size_t)e * Nn * K;

  __shared__ __align__(16) unsigned short As[128 * 40];
  __shared__ __align__(16) unsigned short Bs[128 * 40];
  __shared__ int   s_tok[128];
  __shared__ float s_gate[128];

  int tid  = threadIdx.x;
  int lane = tid & 63;
  int wave = tid >> 6;
  int wm   = (wave >> 1) * 64;
  int wn   = (wave & 1) * 64;
  int lr   = lane & 15;
  int quad = lane >> 4;

  if constexpr (EPI == 1) {
    if (tid < 128) {
      int t = slot_token[(size_t)e * M + m0 + tid];
      s_tok[tid]  = t;
      s_gate[tid] = (t >= 0) ? gate_buf[t] : 0.f;
    }
  }

  floatx4 acc[4][4];
#pragma unroll
  for (int i = 0; i < 4; i++)
#pragma unroll
    for (int j = 0; j < 4; j++) acc[i][j] = (floatx4){0.f, 0.f, 0.f, 0.f};

  int r_a = tid >> 2;          // 0..63
  int c4  = tid & 3;           // 16B chunk within a 64B row

  for (int k0 = 0; k0 < K; k0 += 32) {
    __syncthreads();
#pragma unroll
    for (int i = 0; i < 2; i++) {
      int r = r_a + i * 64;
      uint4 va = *(const uint4*)(Ae + (size_t)(m0 + r) * K + k0 + c4 * 8);
      *(uint4*)(&As[r * 40 + c4 * 8]) = va;
      uint4 vb = *(const uint4*)(Be + (size_t)(n0 + r) * K + k0 + c4 * 8);
      *(uint4*)(&Bs[r * 40 + c4 * 8]) = vb;
    }
    __syncthreads();
    short8 af[4], bf[4];
#pragma unroll
    for (int i = 0; i < 4; i++) {
      af[i] = *(const short8*)(&As[(wm + i * 16 + lr) * 40 + quad * 8]);
      bf[i] = *(const short8*)(&Bs[(wn + i * 16 + lr) * 40 + quad * 8]);
    }
#pragma unroll
    for (int i = 0; i < 4; i++)
#pragma unroll
      for (int j = 0; j < 4; j++)
        acc[i][j] = __builtin_amdgcn_mfma_f32_16x16x32_bf16(af[i], bf[j], acc[i][j], 0, 0, 0);
  }

  // Epilogue. C/D layout: col = lane&15, row = quad*4 + reg (m89-verified).
#pragma unroll
  for (int i = 0; i < 4; i++) {
    int rloc = wm + i * 16 + quad * 4;
#pragma unroll
    for (int j = 0; j < 4; j++) {
      int col = n0 + wn + j * 16 + lr;
      float bz = bias[(size_t)e * Nn + col];
      if constexpr (EPI == 0) {
        size_t base = (size_t)e * M * Nn + (size_t)(m0 + rloc) * Nn + col;
#pragma unroll
        for (int r = 0; r < 4; r++)
          Hout[base + (size_t)r * Nn] = f2bf(gelu_tanh(acc[i][j][r] + bz));
      } else {
#pragma unroll
        for (int r = 0; r < 4; r++) {
          int t = s_tok[rloc + r];
          if (t >= 0)
            Out[(size_t)t * D_ + col] = s_gate[rloc + r] * (acc[i][j][r] + bz);
        }
      }
    }
  }
}

// ---------------------------------------------------------------------------
// K6: finalize scalar losses.
// ---------------------------------------------------------------------------
__global__ void loss_kernel(const float* __restrict__ stats, float* __restrict__ out)
{
  float aux = 0.f;
  for (int i = 0; i < 32; i++) aux += stats[i] * stats[32 + i];
  aux *= 64.f / ((float)B_ * (float)N_ * (float)N_);   // E^2 / (B*N*N)
  out[0] = aux;
  out[1] = stats[64] / (float)(B_ * N_);
}

// ---------------------------------------------------------------------------
extern "C" void kernel_launch(void* const* d_in, const int* in_sizes, int n_in,
                              void* d_out, int out_size, void* d_ws, size_t ws_size,
                              hipStream_t stream)
{
  (void)in_sizes; (void)n_in; (void)ws_size;
  const float* x  = (const float*)d_in[0];
  const float* wr = (const float*)d_in[1];
  const float* w1 = (const float*)d_in[2];
  const float* b1 = (const float*)d_in[3];
  const float* w2 = (const float*)d_in[4];
  const float* b2 = (const float*)d_in[5];
  float* out = (float*)d_out;

  // ws layout (needs ~172 MB total)
  char* ws = (char*)d_ws;
  int*   idx_buf  = (int*)(ws + 0);              // 32 KB
  float* gate_buf = (float*)(ws + 32768);        // 32 KB
  float* stats    = (float*)(ws + 65536);        // 1 KB
  int*   slot_tok = (int*)(ws + 66560);          // 40 KB
  unsigned short* xe  = (unsigned short*)(ws + 107520);    // 20.97 MB
  unsigned short* wbf = (unsigned short*)(ws + 21079040);  // 67.1 MB (w1 then w2)
  unsigned short* hbf = (unsigned short*)(ws + 88187904);  // 83.9 MB; end 172073984

  hipMemsetAsync(d_out, 0, (size_t)out_size * 4, stream);       // dropped tokens -> 0
  hipMemsetAsync(stats, 0, 1024, stream);
  hipMemsetAsync(slot_tok, 0xFF, (size_t)E_ * B_ * C_ * 4, stream);  // -1 = empty slot

  router_kernel<<<(B_ * N_) / 4, 256, 0, stream>>>(x, wr, idx_buf, gate_buf, stats);
  pos_kernel<<<B_ * E_, 64, 0, stream>>>(idx_buf, slot_tok);
  gather_kernel<<<E_ * M_, 256, 0, stream>>>(x, slot_tok, xe);

  // w1 [E][D][H] -> wbf [E][H][D]
  transcast_kernel<<<dim3(H_ / 32, D_ / 32, E_), 256, 0, stream>>>(w1, wbf, D_, H_);
  // h = gelu(xe @ w1 + b1): M=1280, K=1024, Nn=4096
  gemm_kernel<0><<<dim3(H_ / 128, M_ / 128, E_), 256, 0, stream>>>(
      xe, wbf, b1, hbf, nullptr, nullptr, nullptr, M_, D_, H_);
  // w2 [E][H][D] -> wbf [E][D][H]  (reuse buffer; stream-serialized after GEMM1)
  transcast_kernel<<<dim3(D_ / 32, H_ / 32, E_), 256, 0, stream>>>(w2, wbf, H_, D_);
  // out[token] = gate * (h @ w2 + b2): M=1280, K=4096, Nn=1024, scattered
  gemm_kernel<1><<<dim3(D_ / 128, M_ / 128, E_), 256, 0, stream>>>(
      hbf, wbf, b2, nullptr, out, slot_tok, gate_buf, M_, H_, D_);

  loss_kernel<<<1, 1, 0, stream>>>(stats, out + (size_t)B_ * N_ * D_);
}

// Round 2
// 685.331 us; speedup vs baseline: 1.0380x; 1.0380x over previous
//
#include <hip/hip_runtime.h>
#include <hip/hip_bf16.h>
#include <math.h>

// Problem constants (B=4, N=2048, D=1024, E=8, H=4096, C = int(2048*1.25//8)=320)
#define B_ 4
#define N_ 2048
#define D_ 1024
#define E_ 8
#define H_ 4096
#define C_ 320
#define M_ (B_*C_)        // 1280 rows per expert in the grouped GEMMs

typedef __attribute__((ext_vector_type(8))) short short8;   // 8 bf16 = 4 VGPRs (MFMA A/B frag)
typedef __attribute__((ext_vector_type(4))) float floatx4;  // MFMA C/D frag

__device__ __forceinline__ unsigned short f2bf(float f) {
  unsigned u = __builtin_bit_cast(unsigned, f);
  u += 0x7fffu + ((u >> 16) & 1u);          // RNE; inputs are tame (no NaN/Inf)
  return (unsigned short)(u >> 16);
}

// fast tanh-gelu via v_exp_f32: tanh(u) = 1 - 2/(exp(2u)+1). |err| ~1e-6, buried by bf16.
__device__ __forceinline__ float gelu_fast(float x) {
  float u = 0.7978845608028654f * (x + 0.044715f * x * x * x);
  float t = 1.f - 2.f / (__expf(2.f * u) + 1.f);
  return 0.5f * x * (1.f + t);
}

// async global -> LDS, 16 B per lane. LDS dest = wave-uniform base + lane*16 (m97/m104).
__device__ __forceinline__ void gload_lds16(const unsigned short* g, unsigned short* l) {
  __builtin_amdgcn_global_load_lds(
      (const __attribute__((address_space(1))) unsigned int*)g,
      (__attribute__((address_space(3))) unsigned int*)l, 16, 0, 0);
}

// ---------------------------------------------------------------------------
// K1: router. One wave per token; fp64 accumulation to avoid argmax flips vs
// the numpy fp32 reference. stats: [0..31]=count[b*8+e], [32..63]=proxy, [64]=z^2 sum
// ---------------------------------------------------------------------------
__global__ __launch_bounds__(256) void router_kernel(
    const float* __restrict__ x, const float* __restrict__ wr,
    int* __restrict__ idx_buf, float* __restrict__ gate_buf,
    float* __restrict__ stats)
{
  int lane  = threadIdx.x & 63;
  int wave  = threadIdx.x >> 6;
  int token = blockIdx.x * 4 + wave;        // 0..8191
  int b     = token >> 11;                  // N_=2048

  const float* xp = x + (size_t)token * D_ + lane * 16;
  float xv[16];
#pragma unroll
  for (int i = 0; i < 4; i++) {
    float4 v = ((const float4*)xp)[i];
    xv[i*4+0]=v.x; xv[i*4+1]=v.y; xv[i*4+2]=v.z; xv[i*4+3]=v.w;
  }
  double acc[8];
#pragma unroll
  for (int e = 0; e < 8; e++) acc[e] = 0.0;
  const float* wp = wr + (size_t)(lane * 16) * E_;   // w_router is [D][E]
#pragma unroll
  for (int i = 0; i < 16; i++) {
    float xs = xv[i];
#pragma unroll
    for (int e = 0; e < 8; e++) acc[e] += (double)xs * (double)wp[i*8 + e];
  }
  for (int off = 32; off > 0; off >>= 1) {
#pragma unroll
    for (int e = 0; e < 8; e++) acc[e] += __shfl_xor(acc[e], off, 64);
  }

  float l[8];
#pragma unroll
  for (int e = 0; e < 8; e++) l[e] = (float)acc[e];
  float m = l[0]; int best = 0;
#pragma unroll
  for (int e = 1; e < 8; e++) if (l[e] > m) { m = l[e]; best = e; }   // first-max tiebreak
  float p[8], sum = 0.f;
#pragma unroll
  for (int e = 0; e < 8; e++) { p[e] = expf(l[e] - m); sum += p[e]; }
  float inv = 1.f / sum;
#pragma unroll
  for (int e = 0; e < 8; e++) p[e] *= inv;
  float z    = m + logf(sum);
  float gate = inv;                      // softmax at argmax = exp(0)/sum

  __shared__ float s_cnt[8], s_prox[8], s_zsq[1];
  if (threadIdx.x < 8)  { s_cnt[threadIdx.x] = 0.f; s_prox[threadIdx.x] = 0.f; }
  if (threadIdx.x == 8) s_zsq[0] = 0.f;
  __syncthreads();
  if (lane == 0) {
    idx_buf[token]  = best;
    gate_buf[token] = gate;
    atomicAdd(&s_zsq[0], z * z);
    atomicAdd(&s_cnt[best], 1.f);
#pragma unroll
    for (int e = 0; e < 8; e++) atomicAdd(&s_prox[e], p[e]);
  }
  __syncthreads();
  if (threadIdx.x < 8) {
    atomicAdd(&stats[b*8 + threadIdx.x],      s_cnt[threadIdx.x]);
    atomicAdd(&stats[32 + b*8 + threadIdx.x], s_prox[threadIdx.x]);
  }
  if (threadIdx.x == 8) atomicAdd(&stats[64], s_zsq[0]);
}

// ---------------------------------------------------------------------------
// K2: per-(b,e) capacity scan. One wave per (b,e); ballot prefix-sum over N.
// ---------------------------------------------------------------------------
__global__ __launch_bounds__(64) void pos_kernel(
    const int* __restrict__ idx_buf, int* __restrict__ slot_token)
{
  int be = blockIdx.x;                 // 0..31
  int b = be >> 3, e = be & 7;
  int lane = threadIdx.x;
  int base = 0;
  int* out = slot_token + (size_t)(e * B_ + b) * C_;
  for (int n0 = 0; n0 < N_; n0 += 64) {
    int n = n0 + lane;
    bool match = (idx_buf[b * N_ + n] == e);
    unsigned long long mask = __ballot(match);
    int my = base + __popcll(mask & ((1ull << lane) - 1ull));
    if (match && my < C_) out[my] = b * N_ + n;
    base += __popcll(mask);
  }
}

// ---------------------------------------------------------------------------
// K3: gather+cast x rows into xe bf16 [E][M_][D]. One block per slot row.
// ---------------------------------------------------------------------------
__global__ __launch_bounds__(256) void gather_kernel(
    const float* __restrict__ x, const int* __restrict__ slot_token,
    unsigned short* __restrict__ xe)
{
  int row = blockIdx.x;                // 0..E*M_-1  == (e*B+b)*C + c
  int t = slot_token[row];
  int col = threadIdx.x * 4;
  ushort4 o;
  if (t >= 0) {
    float4 v = *(const float4*)(x + (size_t)t * D_ + col);
    o.x = f2bf(v.x); o.y = f2bf(v.y); o.z = f2bf(v.z); o.w = f2bf(v.w);
  } else {
    o.x = 0; o.y = 0; o.z = 0; o.w = 0;
  }
  *(ushort4*)(xe + (size_t)row * D_ + col) = o;
}

// ---------------------------------------------------------------------------
// K4: transpose+cast weights: in fp32 [E][R][Cc] -> out bf16 [E][Cc][R]
// ---------------------------------------------------------------------------
__global__ __launch_bounds__(256) void transcast_kernel(
    const float* __restrict__ in, unsigned short* __restrict__ out, int R, int Cc)
{
  int e = blockIdx.z;
  const float* pin = in + (size_t)e * R * Cc;
  unsigned short* pout = out + (size_t)e * R * Cc;
  __shared__ float T[32][33];
  int r0 = blockIdx.y * 32, c0 = blockIdx.x * 32;
  {
    int lr = threadIdx.x >> 3, lc4 = (threadIdx.x & 7) * 4;
    float4 v = *(const float4*)(pin + (size_t)(r0 + lr) * Cc + c0 + lc4);
    T[lr][lc4+0] = v.x; T[lr][lc4+1] = v.y; T[lr][lc4+2] = v.z; T[lr][lc4+3] = v.w;
  }
  __syncthreads();
  {
    int oc = threadIdx.x >> 3, or4 = (threadIdx.x & 7) * 4;
    ushort4 o;
    o.x = f2bf(T[or4+0][oc]); o.y = f2bf(T[or4+1][oc]);
    o.z = f2bf(T[or4+2][oc]); o.w = f2bf(T[or4+3][oc]);
    *(ushort4*)(pout + (size_t)(c0 + oc) * R + r0 + or4) = o;
  }
}

// ---------------------------------------------------------------------------
// K5: grouped GEMM, m97 pattern: 128x128xBK32 tile, 4 waves x (4x4)
// mfma_f32_16x16x32_bf16, async global_load_lds dwordx4 staging.
// LDS rows UNPADDED (32 bf16 = 64 B): global_load_lds dest = uniform base +
// lane*16 B, so LDS must be contiguous in lane order (m104/m108).
// EPI=0: h = gelu(acc + b1)  -> bf16 Hout [E][M][Nn]
// EPI=1: out[token][col] = gate * (acc + b2), scattered via slot_token
// ---------------------------------------------------------------------------
template<int EPI>
__global__ __launch_bounds__(256) void gemm_kernel(
    const unsigned short* __restrict__ A,    // [E][M][K] bf16
    const unsigned short* __restrict__ BT,   // [E][Nn][K] bf16
    const float* __restrict__ bias,          // [E][Nn] fp32
    unsigned short* __restrict__ Hout,       // EPI=0
    float* __restrict__ Out,                 // EPI=1 (pre-zeroed d_out)
    const int* __restrict__ slot_token,      // EPI=1
    const float* __restrict__ gate_buf,      // EPI=1
    int M, int K, int Nn)
{
  int e  = blockIdx.z;
  int m0 = blockIdx.y * 128;
  int n0 = blockIdx.x * 128;
  const unsigned short* Ae = A  + (size_t)e * M  * K;
  const unsigned short* Be = BT + (size_t)e * Nn * K;

  __shared__ __align__(16) unsigned short As[128 * 32];
  __shared__ __align__(16) unsigned short Bs[128 * 32];
  __shared__ int   s_tok[128];
  __shared__ float s_gate[128];

  int tid  = threadIdx.x;
  int lane = tid & 63;
  int wave = tid >> 6;
  int wm   = (wave >> 1) * 64;
  int wn   = (wave & 1) * 64;
  int lr   = lane & 15;
  int quad = lane >> 4;

  if constexpr (EPI == 1) {
    if (tid < 128) {
      int t = slot_token[(size_t)e * M + m0 + tid];
      s_tok[tid]  = t;
      s_gate[tid] = (t >= 0) ? gate_buf[t] : 0.f;
    }
  }

  floatx4 acc[4][4];
#pragma unroll
  for (int i = 0; i < 4; i++)
#pragma unroll
    for (int j = 0; j < 4; j++) acc[i][j] = (floatx4){0.f, 0.f, 0.f, 0.f};

  // Async-staging geometry: wave w stages rows [w*32, w*32+32) of each tile
  // in two global_load_lds_dwordx4 (16 rows x 64 B = 1024 B each).
  // Within an instruction: lane i -> row base+ (i>>2), k-chunk (i&3)*8.
  int rA0 = wave * 32 + (lane >> 2);          // rows for q=0 instruction
  int kcc = (lane & 3) * 8;
  const unsigned short* Agp0 = Ae + (size_t)(m0 + rA0)      * K + kcc;
  const unsigned short* Agp1 = Ae + (size_t)(m0 + rA0 + 16) * K + kcc;
  const unsigned short* Bgp0 = Be + (size_t)(n0 + rA0)      * K + kcc;
  const unsigned short* Bgp1 = Be + (size_t)(n0 + rA0 + 16) * K + kcc;
  unsigned short* ldsA0 = &As[(wave * 32) * 32];
  unsigned short* ldsA1 = &As[(wave * 32 + 16) * 32];
  unsigned short* ldsB0 = &Bs[(wave * 32) * 32];
  unsigned short* ldsB1 = &Bs[(wave * 32 + 16) * 32];

  for (int k0 = 0; k0 < K; k0 += 32) {
    __syncthreads();
    gload_lds16(Agp0, ldsA0);
    gload_lds16(Agp1, ldsA1);
    gload_lds16(Bgp0, ldsB0);
    gload_lds16(Bgp1, ldsB1);
    Agp0 += 32; Agp1 += 32; Bgp0 += 32; Bgp1 += 32;
    __syncthreads();   // compiler emits vmcnt(0) drain here (m97)
    short8 af[4], bf[4];
#pragma unroll
    for (int i = 0; i < 4; i++) {
      af[i] = *(const short8*)(&As[(wm + i * 16 + lr) * 32 + quad * 8]);
      bf[i] = *(const short8*)(&Bs[(wn + i * 16 + lr) * 32 + quad * 8]);
    }
#pragma unroll
    for (int i = 0; i < 4; i++)
#pragma unroll
      for (int j = 0; j < 4; j++)
        acc[i][j] = __builtin_amdgcn_mfma_f32_16x16x32_bf16(af[i], bf[j], acc[i][j], 0, 0, 0);
  }

  // Epilogue. C/D layout: col = lane&15, row = quad*4 + reg (m89-verified).
#pragma unroll
  for (int i = 0; i < 4; i++) {
    int rloc = wm + i * 16 + quad * 4;
#pragma unroll
    for (int j = 0; j < 4; j++) {
      int col = n0 + wn + j * 16 + lr;
      float bz = bias[(size_t)e * Nn + col];
      if constexpr (EPI == 0) {
        size_t base = (size_t)e * M * Nn + (size_t)(m0 + rloc) * Nn + col;
#pragma unroll
        for (int r = 0; r < 4; r++)
          Hout[base + (size_t)r * Nn] = f2bf(gelu_fast(acc[i][j][r] + bz));
      } else {
#pragma unroll
        for (int r = 0; r < 4; r++) {
          int t = s_tok[rloc + r];
          if (t >= 0)
            Out[(size_t)t * D_ + col] = s_gate[rloc + r] * (acc[i][j][r] + bz);
        }
      }
    }
  }
}

// ---------------------------------------------------------------------------
// K6: finalize scalar losses.
// ---------------------------------------------------------------------------
__global__ void loss_kernel(const float* __restrict__ stats, float* __restrict__ out)
{
  float aux = 0.f;
  for (int i = 0; i < 32; i++) aux += stats[i] * stats[32 + i];
  aux *= 64.f / ((float)B_ * (float)N_ * (float)N_);   // E^2 / (B*N*N)
  out[0] = aux;
  out[1] = stats[64] / (float)(B_ * N_);
}

// ---------------------------------------------------------------------------
extern "C" void kernel_launch(void* const* d_in, const int* in_sizes, int n_in,
                              void* d_out, int out_size, void* d_ws, size_t ws_size,
                              hipStream_t stream)
{
  (void)in_sizes; (void)n_in; (void)ws_size;
  const float* x  = (const float*)d_in[0];
  const float* wr = (const float*)d_in[1];
  const float* w1 = (const float*)d_in[2];
  const float* b1 = (const float*)d_in[3];
  const float* w2 = (const float*)d_in[4];
  const float* b2 = (const float*)d_in[5];
  float* out = (float*)d_out;

  // ws layout (~172 MB total)
  char* ws = (char*)d_ws;
  int*   idx_buf  = (int*)(ws + 0);              // 32 KB
  float* gate_buf = (float*)(ws + 32768);        // 32 KB
  float* stats    = (float*)(ws + 65536);        // 1 KB
  int*   slot_tok = (int*)(ws + 66560);          // 40 KB
  unsigned short* xe  = (unsigned short*)(ws + 107520);    // 20.97 MB
  unsigned short* wbf = (unsigned short*)(ws + 21079040);  // 67.1 MB (w1 then w2)
  unsigned short* hbf = (unsigned short*)(ws + 88187904);  // 83.9 MB; end 172073984

  hipMemsetAsync(d_out, 0, (size_t)out_size * 4, stream);       // dropped tokens -> 0
  hipMemsetAsync(stats, 0, 1024, stream);
  hipMemsetAsync(slot_tok, 0xFF, (size_t)E_ * B_ * C_ * 4, stream);  // -1 = empty slot

  router_kernel<<<(B_ * N_) / 4, 256, 0, stream>>>(x, wr, idx_buf, gate_buf, stats);
  pos_kernel<<<B_ * E_, 64, 0, stream>>>(idx_buf, slot_tok);
  gather_kernel<<<E_ * M_, 256, 0, stream>>>(x, slot_tok, xe);

  // w1 [E][D][H] -> wbf [E][H][D]
  transcast_kernel<<<dim3(H_ / 32, D_ / 32, E_), 256, 0, stream>>>(w1, wbf, D_, H_);
  // h = gelu(xe @ w1 + b1): M=1280, K=1024, Nn=4096
  gemm_kernel<0><<<dim3(H_ / 128, M_ / 128, E_), 256, 0, stream>>>(
      xe, wbf, b1, hbf, nullptr, nullptr, nullptr, M_, D_, H_);
  // w2 [E][H][D] -> wbf [E][D][H]  (reuse buffer; stream-serialized after GEMM1)
  transcast_kernel<<<dim3(D_ / 32, H_ / 32, E_), 256, 0, stream>>>(w2, wbf, H_, D_);
  // out[token] = gate * (h @ w2 + b2): M=1280, K=4096, Nn=1024, scattered
  gemm_kernel<1><<<dim3(D_ / 128, M_ / 128, E_), 256, 0, stream>>>(
      hbf, wbf, b2, nullptr, out, slot_tok, gate_buf, M_, H_, D_);

  loss_kernel<<<1, 1, 0, stream>>>(stats, out + (size_t)B_ * N_ * D_);
}

// Round 3
// 673.378 us; speedup vs baseline: 1.0564x; 1.0178x over previous
//
#include <hip/hip_runtime.h>
#include <hip/hip_bf16.h>
#include <math.h>

// Problem constants (B=4, N=2048, D=1024, E=8, H=4096, C = int(2048*1.25//8)=320)
#define B_ 4
#define N_ 2048
#define D_ 1024
#define E_ 8
#define H_ 4096
#define C_ 320
#define M_ (B_*C_)        // 1280 rows per expert in the grouped GEMMs

typedef __attribute__((ext_vector_type(8))) short short8;   // 8 bf16 = 4 VGPRs (MFMA A/B frag)
typedef __attribute__((ext_vector_type(4))) float floatx4;  // MFMA C/D frag

__device__ __forceinline__ unsigned short f2bf(float f) {
  unsigned u = __builtin_bit_cast(unsigned, f);
  u += 0x7fffu + ((u >> 16) & 1u);          // RNE; inputs are tame (no NaN/Inf)
  return (unsigned short)(u >> 16);
}

// fast tanh-gelu via v_exp_f32: tanh(u) = 1 - 2/(exp(2u)+1). |err| ~1e-6, buried by bf16.
__device__ __forceinline__ float gelu_fast(float x) {
  float u = 0.7978845608028654f * (x + 0.044715f * x * x * x);
  float t = 1.f - 2.f / (__expf(2.f * u) + 1.f);
  return 0.5f * x * (1.f + t);
}

// async global -> LDS, 16 B per lane. LDS dest = wave-uniform base + lane*16 (m97/m104).
__device__ __forceinline__ void gload_lds16(const unsigned short* g, unsigned short* l) {
  __builtin_amdgcn_global_load_lds(
      (const __attribute__((address_space(1))) unsigned int*)g,
      (__attribute__((address_space(3))) unsigned int*)l, 16, 0, 0);
}

// ---------------------------------------------------------------------------
// K1: router. One wave per token; fp64 accumulation to avoid argmax flips vs
// the numpy fp32 reference. stats: [0..31]=count[b*8+e], [32..63]=proxy, [64]=z^2 sum
// ---------------------------------------------------------------------------
__global__ __launch_bounds__(256) void router_kernel(
    const float* __restrict__ x, const float* __restrict__ wr,
    int* __restrict__ idx_buf, float* __restrict__ gate_buf,
    float* __restrict__ stats)
{
  int lane  = threadIdx.x & 63;
  int wave  = threadIdx.x >> 6;
  int token = blockIdx.x * 4 + wave;        // 0..8191
  int b     = token >> 11;                  // N_=2048

  const float* xp = x + (size_t)token * D_ + lane * 16;
  float xv[16];
#pragma unroll
  for (int i = 0; i < 4; i++) {
    float4 v = ((const float4*)xp)[i];
    xv[i*4+0]=v.x; xv[i*4+1]=v.y; xv[i*4+2]=v.z; xv[i*4+3]=v.w;
  }
  double acc[8];
#pragma unroll
  for (int e = 0; e < 8; e++) acc[e] = 0.0;
  const float* wp = wr + (size_t)(lane * 16) * E_;   // w_router is [D][E]
#pragma unroll
  for (int i = 0; i < 16; i++) {
    float xs = xv[i];
#pragma unroll
    for (int e = 0; e < 8; e++) acc[e] += (double)xs * (double)wp[i*8 + e];
  }
  for (int off = 32; off > 0; off >>= 1) {
#pragma unroll
    for (int e = 0; e < 8; e++) acc[e] += __shfl_xor(acc[e], off, 64);
  }

  float l[8];
#pragma unroll
  for (int e = 0; e < 8; e++) l[e] = (float)acc[e];
  float m = l[0]; int best = 0;
#pragma unroll
  for (int e = 1; e < 8; e++) if (l[e] > m) { m = l[e]; best = e; }   // first-max tiebreak
  float p[8], sum = 0.f;
#pragma unroll
  for (int e = 0; e < 8; e++) { p[e] = expf(l[e] - m); sum += p[e]; }
  float inv = 1.f / sum;
#pragma unroll
  for (int e = 0; e < 8; e++) p[e] *= inv;
  float z    = m + logf(sum);
  float gate = inv;                      // softmax at argmax = exp(0)/sum

  __shared__ float s_cnt[8], s_prox[8], s_zsq[1];
  if (threadIdx.x < 8)  { s_cnt[threadIdx.x] = 0.f; s_prox[threadIdx.x] = 0.f; }
  if (threadIdx.x == 8) s_zsq[0] = 0.f;
  __syncthreads();
  if (lane == 0) {
    idx_buf[token]  = best;
    gate_buf[token] = gate;
    atomicAdd(&s_zsq[0], z * z);
    atomicAdd(&s_cnt[best], 1.f);
#pragma unroll
    for (int e = 0; e < 8; e++) atomicAdd(&s_prox[e], p[e]);
  }
  __syncthreads();
  if (threadIdx.x < 8) {
    atomicAdd(&stats[b*8 + threadIdx.x],      s_cnt[threadIdx.x]);
    atomicAdd(&stats[32 + b*8 + threadIdx.x], s_prox[threadIdx.x]);
  }
  if (threadIdx.x == 8) atomicAdd(&stats[64], s_zsq[0]);
}

// ---------------------------------------------------------------------------
// K2: per-(b,e) capacity scan. One wave per (b,e); ballot prefix-sum over N.
// ---------------------------------------------------------------------------
__global__ __launch_bounds__(64) void pos_kernel(
    const int* __restrict__ idx_buf, int* __restrict__ slot_token)
{
  int be = blockIdx.x;                 // 0..31
  int b = be >> 3, e = be & 7;
  int lane = threadIdx.x;
  int base = 0;
  int* out = slot_token + (size_t)(e * B_ + b) * C_;
  for (int n0 = 0; n0 < N_; n0 += 64) {
    int n = n0 + lane;
    bool match = (idx_buf[b * N_ + n] == e);
    unsigned long long mask = __ballot(match);
    int my = base + __popcll(mask & ((1ull << lane) - 1ull));
    if (match && my < C_) out[my] = b * N_ + n;
    base += __popcll(mask);
  }
}

// ---------------------------------------------------------------------------
// K3: gather+cast x rows into xe bf16 [E][M_][D]. One block per slot row.
// ---------------------------------------------------------------------------
__global__ __launch_bounds__(256) void gather_kernel(
    const float* __restrict__ x, const int* __restrict__ slot_token,
    unsigned short* __restrict__ xe)
{
  int row = blockIdx.x;                // 0..E*M_-1  == (e*B+b)*C + c
  int t = slot_token[row];
  int col = threadIdx.x * 4;
  ushort4 o;
  if (t >= 0) {
    float4 v = *(const float4*)(x + (size_t)t * D_ + col);
    o.x = f2bf(v.x); o.y = f2bf(v.y); o.z = f2bf(v.z); o.w = f2bf(v.w);
  } else {
    o.x = 0; o.y = 0; o.z = 0; o.w = 0;
  }
  *(ushort4*)(xe + (size_t)row * D_ + col) = o;
}

// ---------------------------------------------------------------------------
// K4: transpose+cast weights: in fp32 [E][R][Cc] -> out bf16 [E][Cc][R].
// 64x64 tile; fully-coalesced reads (64B segments) and writes (128B rows:
// 16 lanes x ushort4 per output row). LDS padded to 65 -> frag reads 2-way
// bank aliased = free (m136).
// ---------------------------------------------------------------------------
__global__ __launch_bounds__(256) void transcast_kernel(
    const float* __restrict__ in, unsigned short* __restrict__ out, int R, int Cc)
{
  int e = blockIdx.z;
  const float* pin = in + (size_t)e * R * Cc;
  unsigned short* pout = out + (size_t)e * R * Cc;
  __shared__ float T[64][65];
  int r0 = blockIdx.y * 64, c0 = blockIdx.x * 64;
  {
    int row = threadIdx.x >> 2;               // 0..63
    int cb  = (threadIdx.x & 3) * 4;          // 0,4,8,12
#pragma unroll
    for (int p = 0; p < 4; p++) {
      int col = cb + p * 16;
      float4 v = *(const float4*)(pin + (size_t)(r0 + row) * Cc + c0 + col);
      T[row][col+0] = v.x; T[row][col+1] = v.y; T[row][col+2] = v.z; T[row][col+3] = v.w;
    }
  }
  __syncthreads();
  {
    int ocb = threadIdx.x >> 4;               // 0..15
    int or4 = (threadIdx.x & 15) * 4;         // 0..60
#pragma unroll
    for (int p = 0; p < 4; p++) {
      int oc = ocb + p * 16;
      ushort4 o;
      o.x = f2bf(T[or4+0][oc]); o.y = f2bf(T[or4+1][oc]);
      o.z = f2bf(T[or4+2][oc]); o.w = f2bf(T[or4+3][oc]);
      *(ushort4*)(pout + (size_t)(c0 + oc) * R + r0 + or4) = o;
    }
  }
}

// ---------------------------------------------------------------------------
// K5: grouped GEMM, m97 pattern + 2-stage LDS double-buffer.
// 128x128xBK32 tile, 4 waves x (4x4) mfma_f32_16x16x32_bf16, async
// global_load_lds dwordx4 staging. Stage t+1's loads are issued right after
// the barrier that releases compute of stage t, so the next barrier's
// vmcnt(0) drain finds them ~1 compute-phase (~350 cyc) old instead of 0 —
// intra-block latency hiding for the 2.5-blocks/CU grids where inter-block
// overlap (m114) is unavailable.
// LDS rows UNPADDED (32 bf16 = 64 B): global_load_lds dest = uniform base +
// lane*16 B (m104/m108).
// EPI=0: h = gelu(acc + b1)  -> bf16 Hout [E][M][Nn]
// EPI=1: out[token][col] = gate * (acc + b2), scattered via slot_token
// ---------------------------------------------------------------------------
template<int EPI>
__global__ __launch_bounds__(256) void gemm_kernel(
    const unsigned short* __restrict__ A,    // [E][M][K] bf16
    const unsigned short* __restrict__ BT,   // [E][Nn][K] bf16
    const float* __restrict__ bias,          // [E][Nn] fp32
    unsigned short* __restrict__ Hout,       // EPI=0
    float* __restrict__ Out,                 // EPI=1 (pre-zeroed d_out)
    const int* __restrict__ slot_token,      // EPI=1
    const float* __restrict__ gate_buf,      // EPI=1
    int M, int K, int Nn)
{
  int e  = blockIdx.z;
  int m0 = blockIdx.y * 128;
  int n0 = blockIdx.x * 128;
  const unsigned short* Ae = A  + (size_t)e * M  * K;
  const unsigned short* Be = BT + (size_t)e * Nn * K;

  __shared__ __align__(16) unsigned short As[2][128 * 32];
  __shared__ __align__(16) unsigned short Bs[2][128 * 32];
  __shared__ int   s_tok[128];
  __shared__ float s_gate[128];

  int tid  = threadIdx.x;
  int lane = tid & 63;
  int wave = tid >> 6;
  int wm   = (wave >> 1) * 64;
  int wn   = (wave & 1) * 64;
  int lr   = lane & 15;
  int quad = lane >> 4;

  if constexpr (EPI == 1) {
    if (tid < 128) {
      int t = slot_token[(size_t)e * M + m0 + tid];
      s_tok[tid]  = t;
      s_gate[tid] = (t >= 0) ? gate_buf[t] : 0.f;
    }
  }

  floatx4 acc[4][4];
#pragma unroll
  for (int i = 0; i < 4; i++)
#pragma unroll
    for (int j = 0; j < 4; j++) acc[i][j] = (floatx4){0.f, 0.f, 0.f, 0.f};

  // Staging geometry: wave w stages rows [w*32, w*32+32) of each tile in two
  // global_load_lds_dwordx4 (16 rows x 64 B each); lane i -> row +(i>>2),
  // k-chunk (i&3)*8.
  int rA0 = wave * 32 + (lane >> 2);
  int kcc = (lane & 3) * 8;
  const unsigned short* Ag0 = Ae + (size_t)(m0 + rA0)      * K + kcc;
  const unsigned short* Ag1 = Ae + (size_t)(m0 + rA0 + 16) * K + kcc;
  const unsigned short* Bg0 = Be + (size_t)(n0 + rA0)      * K + kcc;
  const unsigned short* Bg1 = Be + (size_t)(n0 + rA0 + 16) * K + kcc;
  const unsigned offA0 = (wave * 32) * 32;
  const unsigned offA1 = (wave * 32 + 16) * 32;

  // Prologue: stage 0 -> buf 0 (LDS untouched so far; no barrier needed).
  gload_lds16(Ag0, &As[0][offA0]);
  gload_lds16(Ag1, &As[0][offA1]);
  gload_lds16(Bg0, &Bs[0][offA0]);
  gload_lds16(Bg1, &Bs[0][offA1]);
  Ag0 += 32; Ag1 += 32; Bg0 += 32; Bg1 += 32;

  int nIter = K >> 5;
  int buf = 0;
  for (int it = 0; it < nIter; ++it) {
    __syncthreads();   // drains vmcnt -> As/Bs[buf] ready; prior compute on buf^1 done
    if (it + 1 < nIter) {
      gload_lds16(Ag0, &As[buf ^ 1][offA0]);
      gload_lds16(Ag1, &As[buf ^ 1][offA1]);
      gload_lds16(Bg0, &Bs[buf ^ 1][offA0]);
      gload_lds16(Bg1, &Bs[buf ^ 1][offA1]);
      Ag0 += 32; Ag1 += 32; Bg0 += 32; Bg1 += 32;
    }
    short8 af[4], bf[4];
#pragma unroll
    for (int i = 0; i < 4; i++) {
      af[i] = *(const short8*)(&As[buf][(wm + i * 16 + lr) * 32 + quad * 8]);
      bf[i] = *(const short8*)(&Bs[buf][(wn + i * 16 + lr) * 32 + quad * 8]);
    }
#pragma unroll
    for (int i = 0; i < 4; i++)
#pragma unroll
      for (int j = 0; j < 4; j++)
        acc[i][j] = __builtin_amdgcn_mfma_f32_16x16x32_bf16(af[i], bf[j], acc[i][j], 0, 0, 0);
    buf ^= 1;
  }

  // Epilogue. C/D layout: col = lane&15, row = quad*4 + reg (m89-verified).
#pragma unroll
  for (int i = 0; i < 4; i++) {
    int rloc = wm + i * 16 + quad * 4;
#pragma unroll
    for (int j = 0; j < 4; j++) {
      int col = n0 + wn + j * 16 + lr;
      float bz = bias[(size_t)e * Nn + col];
      if constexpr (EPI == 0) {
        size_t base = (size_t)e * M * Nn + (size_t)(m0 + rloc) * Nn + col;
#pragma unroll
        for (int r = 0; r < 4; r++)
          Hout[base + (size_t)r * Nn] = f2bf(gelu_fast(acc[i][j][r] + bz));
      } else {
#pragma unroll
        for (int r = 0; r < 4; r++) {
          int t = s_tok[rloc + r];
          if (t >= 0)
            Out[(size_t)t * D_ + col] = s_gate[rloc + r] * (acc[i][j][r] + bz);
        }
      }
    }
  }
}

// ---------------------------------------------------------------------------
// K6: finalize scalar losses.
// ---------------------------------------------------------------------------
__global__ void loss_kernel(const float* __restrict__ stats, float* __restrict__ out)
{
  float aux = 0.f;
  for (int i = 0; i < 32; i++) aux += stats[i] * stats[32 + i];
  aux *= 64.f / ((float)B_ * (float)N_ * (float)N_);   // E^2 / (B*N*N)
  out[0] = aux;
  out[1] = stats[64] / (float)(B_ * N_);
}

// ---------------------------------------------------------------------------
extern "C" void kernel_launch(void* const* d_in, const int* in_sizes, int n_in,
                              void* d_out, int out_size, void* d_ws, size_t ws_size,
                              hipStream_t stream)
{
  (void)in_sizes; (void)n_in; (void)ws_size;
  const float* x  = (const float*)d_in[0];
  const float* wr = (const float*)d_in[1];
  const float* w1 = (const float*)d_in[2];
  const float* b1 = (const float*)d_in[3];
  const float* w2 = (const float*)d_in[4];
  const float* b2 = (const float*)d_in[5];
  float* out = (float*)d_out;

  // ws layout (~172 MB total)
  char* ws = (char*)d_ws;
  int*   idx_buf  = (int*)(ws + 0);              // 32 KB
  float* gate_buf = (float*)(ws + 32768);        // 32 KB
  float* stats    = (float*)(ws + 65536);        // 1 KB
  int*   slot_tok = (int*)(ws + 66560);          // 40 KB
  unsigned short* xe  = (unsigned short*)(ws + 107520);    // 20.97 MB
  unsigned short* wbf = (unsigned short*)(ws + 21079040);  // 67.1 MB (w1 then w2)
  unsigned short* hbf = (unsigned short*)(ws + 88187904);  // 83.9 MB; end 172073984

  hipMemsetAsync(d_out, 0, (size_t)out_size * 4, stream);       // dropped tokens -> 0
  hipMemsetAsync(stats, 0, 1024, stream);
  hipMemsetAsync(slot_tok, 0xFF, (size_t)E_ * B_ * C_ * 4, stream);  // -1 = empty slot

  router_kernel<<<(B_ * N_) / 4, 256, 0, stream>>>(x, wr, idx_buf, gate_buf, stats);
  pos_kernel<<<B_ * E_, 64, 0, stream>>>(idx_buf, slot_tok);
  gather_kernel<<<E_ * M_, 256, 0, stream>>>(x, slot_tok, xe);

  // w1 [E][D][H] -> wbf [E][H][D]
  transcast_kernel<<<dim3(H_ / 64, D_ / 64, E_), 256, 0, stream>>>(w1, wbf, D_, H_);
  // h = gelu(xe @ w1 + b1): M=1280, K=1024, Nn=4096
  gemm_kernel<0><<<dim3(H_ / 128, M_ / 128, E_), 256, 0, stream>>>(
      xe, wbf, b1, hbf, nullptr, nullptr, nullptr, M_, D_, H_);
  // w2 [E][H][D] -> wbf [E][D][H]  (reuse buffer; stream-serialized after GEMM1)
  transcast_kernel<<<dim3(D_ / 64, H_ / 64, E_), 256, 0, stream>>>(w2, wbf, H_, D_);
  // out[token] = gate * (h @ w2 + b2): M=1280, K=4096, Nn=1024, scattered
  gemm_kernel<1><<<dim3(D_ / 128, M_ / 128, E_), 256, 0, stream>>>(
      hbf, wbf, b2, nullptr, out, slot_tok, gate_buf, M_, H_, D_);

  loss_kernel<<<1, 1, 0, stream>>>(stats, out + (size_t)B_ * N_ * D_);
}

// Round 4
// 643.649 us; speedup vs baseline: 1.1052x; 1.0462x over previous
//
#include <hip/hip_runtime.h>
#include <hip/hip_bf16.h>
#include <math.h>

// Problem constants (B=4, N=2048, D=1024, E=8, H=4096, C = int(2048*1.25//8)=320)
#define B_ 4
#define N_ 2048
#define D_ 1024
#define E_ 8
#define H_ 4096
#define C_ 320
#define M_ (B_*C_)        // 1280 rows per expert in the grouped GEMMs

typedef __attribute__((ext_vector_type(8))) short short8;   // 8 bf16 = 4 VGPRs (MFMA A/B frag)
typedef __attribute__((ext_vector_type(4))) float floatx4;  // MFMA C/D frag

__device__ __forceinline__ unsigned short f2bf(float f) {
  unsigned u = __builtin_bit_cast(unsigned, f);
  u += 0x7fffu + ((u >> 16) & 1u);          // RNE; inputs are tame (no NaN/Inf)
  return (unsigned short)(u >> 16);
}

// fast tanh-gelu via v_exp_f32: tanh(u) = 1 - 2/(exp(2u)+1). |err| ~1e-6, buried by bf16.
__device__ __forceinline__ float gelu_fast(float x) {
  float u = 0.7978845608028654f * (x + 0.044715f * x * x * x);
  float t = 1.f - 2.f / (__expf(2.f * u) + 1.f);
  return 0.5f * x * (1.f + t);
}

// async global -> LDS, 16 B per lane. LDS dest = wave-uniform base + lane*16 (m97/m104).
__device__ __forceinline__ void gload_lds16(const unsigned short* g, unsigned short* l) {
  __builtin_amdgcn_global_load_lds(
      (const __attribute__((address_space(1))) unsigned int*)g,
      (__attribute__((address_space(3))) unsigned int*)l, 16, 0, 0);
}

// ---------------------------------------------------------------------------
// K1: router. One wave per token; fp64 accumulation to avoid argmax flips vs
// the numpy fp32 reference. stats: [0..31]=count[b*8+e], [32..63]=proxy, [64]=z^2 sum
// ---------------------------------------------------------------------------
__global__ __launch_bounds__(256) void router_kernel(
    const float* __restrict__ x, const float* __restrict__ wr,
    int* __restrict__ idx_buf, float* __restrict__ gate_buf,
    float* __restrict__ stats)
{
  int lane  = threadIdx.x & 63;
  int wave  = threadIdx.x >> 6;
  int token = blockIdx.x * 4 + wave;        // 0..8191
  int b     = token >> 11;                  // N_=2048

  const float* xp = x + (size_t)token * D_ + lane * 16;
  float xv[16];
#pragma unroll
  for (int i = 0; i < 4; i++) {
    float4 v = ((const float4*)xp)[i];
    xv[i*4+0]=v.x; xv[i*4+1]=v.y; xv[i*4+2]=v.z; xv[i*4+3]=v.w;
  }
  double acc[8];
#pragma unroll
  for (int e = 0; e < 8; e++) acc[e] = 0.0;
  const float* wp = wr + (size_t)(lane * 16) * E_;   // w_router is [D][E]
#pragma unroll
  for (int i = 0; i < 16; i++) {
    float xs = xv[i];
#pragma unroll
    for (int e = 0; e < 8; e++) acc[e] += (double)xs * (double)wp[i*8 + e];
  }
  for (int off = 32; off > 0; off >>= 1) {
#pragma unroll
    for (int e = 0; e < 8; e++) acc[e] += __shfl_xor(acc[e], off, 64);
  }

  float l[8];
#pragma unroll
  for (int e = 0; e < 8; e++) l[e] = (float)acc[e];
  float m = l[0]; int best = 0;
#pragma unroll
  for (int e = 1; e < 8; e++) if (l[e] > m) { m = l[e]; best = e; }   // first-max tiebreak
  float p[8], sum = 0.f;
#pragma unroll
  for (int e = 0; e < 8; e++) { p[e] = expf(l[e] - m); sum += p[e]; }
  float inv = 1.f / sum;
#pragma unroll
  for (int e = 0; e < 8; e++) p[e] *= inv;
  float z    = m + logf(sum);
  float gate = inv;                      // softmax at argmax = exp(0)/sum

  __shared__ float s_cnt[8], s_prox[8], s_zsq[1];
  if (threadIdx.x < 8)  { s_cnt[threadIdx.x] = 0.f; s_prox[threadIdx.x] = 0.f; }
  if (threadIdx.x == 8) s_zsq[0] = 0.f;
  __syncthreads();
  if (lane == 0) {
    idx_buf[token]  = best;
    gate_buf[token] = gate;
    atomicAdd(&s_zsq[0], z * z);
    atomicAdd(&s_cnt[best], 1.f);
#pragma unroll
    for (int e = 0; e < 8; e++) atomicAdd(&s_prox[e], p[e]);
  }
  __syncthreads();
  if (threadIdx.x < 8) {
    atomicAdd(&stats[b*8 + threadIdx.x],      s_cnt[threadIdx.x]);
    atomicAdd(&stats[32 + b*8 + threadIdx.x], s_prox[threadIdx.x]);
  }
  if (threadIdx.x == 8) atomicAdd(&stats[64], s_zsq[0]);
}

// ---------------------------------------------------------------------------
// K2: per-(b,e) capacity scan + loss finalize (folded; stats ready since the
// router kernel completed before this launch).
// ---------------------------------------------------------------------------
__global__ __launch_bounds__(64) void pos_kernel(
    const int* __restrict__ idx_buf, int* __restrict__ slot_token,
    const float* __restrict__ stats, float* __restrict__ loss_out)
{
  int be = blockIdx.x;                 // 0..31
  int b = be >> 3, e = be & 7;
  int lane = threadIdx.x;
  int base = 0;
  int* out = slot_token + (size_t)(e * B_ + b) * C_;
  for (int n0 = 0; n0 < N_; n0 += 64) {
    int n = n0 + lane;
    bool match = (idx_buf[b * N_ + n] == e);
    unsigned long long mask = __ballot(match);
    int my = base + __popcll(mask & ((1ull << lane) - 1ull));
    if (match && my < C_) out[my] = b * N_ + n;
    base += __popcll(mask);
  }
  if (be == 0 && lane == 0) {
    float aux = 0.f;
    for (int i = 0; i < 32; i++) aux += stats[i] * stats[32 + i];
    aux *= 64.f / ((float)B_ * (float)N_ * (float)N_);   // E^2 / (B*N*N)
    loss_out[0] = aux;
    loss_out[1] = stats[64] / (float)(B_ * N_);
  }
}

// ---------------------------------------------------------------------------
// K3: gather+cast x rows into xe bf16 [E][M_][D]. One block per slot row.
// ---------------------------------------------------------------------------
__global__ __launch_bounds__(256) void gather_kernel(
    const float* __restrict__ x, const int* __restrict__ slot_token,
    unsigned short* __restrict__ xe)
{
  int row = blockIdx.x;                // 0..E*M_-1  == (e*B+b)*C + c
  int t = slot_token[row];
  int col = threadIdx.x * 4;
  ushort4 o;
  if (t >= 0) {
    float4 v = *(const float4*)(x + (size_t)t * D_ + col);
    o.x = f2bf(v.x); o.y = f2bf(v.y); o.z = f2bf(v.z); o.w = f2bf(v.w);
  } else {
    o.x = 0; o.y = 0; o.z = 0; o.w = 0;
  }
  *(ushort4*)(xe + (size_t)row * D_ + col) = o;
}

// ---------------------------------------------------------------------------
// K4: transpose+cast weights: in fp32 [E][R][Cc] -> out bf16 [E][Cc][R].
// 64x64 tile; coalesced reads/writes; LDS padded to 65.
// ---------------------------------------------------------------------------
__global__ __launch_bounds__(256) void transcast_kernel(
    const float* __restrict__ in, unsigned short* __restrict__ out, int R, int Cc)
{
  int e = blockIdx.z;
  const float* pin = in + (size_t)e * R * Cc;
  unsigned short* pout = out + (size_t)e * R * Cc;
  __shared__ float T[64][65];
  int r0 = blockIdx.y * 64, c0 = blockIdx.x * 64;
  {
    int row = threadIdx.x >> 2;               // 0..63
    int cb  = (threadIdx.x & 3) * 4;          // 0,4,8,12
#pragma unroll
    for (int p = 0; p < 4; p++) {
      int col = cb + p * 16;
      float4 v = *(const float4*)(pin + (size_t)(r0 + row) * Cc + c0 + col);
      T[row][col+0] = v.x; T[row][col+1] = v.y; T[row][col+2] = v.z; T[row][col+3] = v.w;
    }
  }
  __syncthreads();
  {
    int ocb = threadIdx.x >> 4;               // 0..15
    int or4 = (threadIdx.x & 15) * 4;         // 0..60
#pragma unroll
    for (int p = 0; p < 4; p++) {
      int oc = ocb + p * 16;
      ushort4 o;
      o.x = f2bf(T[or4+0][oc]); o.y = f2bf(T[or4+1][oc]);
      o.z = f2bf(T[or4+2][oc]); o.w = f2bf(T[or4+3][oc]);
      *(ushort4*)(pout + (size_t)(c0 + oc) * R + r0 + or4) = o;
    }
  }
}

// ---------------------------------------------------------------------------
// K5: grouped GEMM, m97 pattern + dbuf + EXPERT->XCD PINNING.
// 1-D grid; block b -> expert = b % 8 (round-robin block->XCD map, m09), so
// each XCD's private L2 only ever sees ONE expert's weight slab. Slot order
// n-outer/m-inner: the ~64 concurrent blocks per XCD share the expert A-slab
// (L2-resident) + a handful of B n-strips. Targets the observed 4.4x
// L2-miss over-fetch (390 MB vs 88-150 MB compulsory, EA pipe pinned at
// ~2.5-2.7 TB/s across R1-R3).
// EPI=0: h = gelu(acc + b1)  -> bf16 Hout [E][M][Nn]
// EPI=1: out[token][col] = gate * (acc + b2), scattered via slot_token
// ---------------------------------------------------------------------------
template<int EPI>
__global__ __launch_bounds__(256) void gemm_kernel(
    const unsigned short* __restrict__ A,    // [E][M][K] bf16
    const unsigned short* __restrict__ BT,   // [E][Nn][K] bf16
    const float* __restrict__ bias,          // [E][Nn] fp32
    unsigned short* __restrict__ Hout,       // EPI=0
    float* __restrict__ Out,                 // EPI=1 (pre-zeroed d_out)
    const int* __restrict__ slot_token,      // EPI=1
    const float* __restrict__ gate_buf,      // EPI=1
    int M, int K, int Nn, int MT)            // MT = M/128 tiles
{
  int e  = blockIdx.x & 7;                  // expert == XCD (round-robin map)
  int s  = blockIdx.x >> 3;                 // slot within expert
  int m0 = (s % MT) * 128;                  // m-inner
  int n0 = (s / MT) * 128;                  // n-outer
  const unsigned short* Ae = A  + (size_t)e * M  * K;
  const unsigned short* Be = BT + (size_t)e * Nn * K;

  __shared__ __align__(16) unsigned short As[2][128 * 32];
  __shared__ __align__(16) unsigned short Bs[2][128 * 32];
  __shared__ int   s_tok[128];
  __shared__ float s_gate[128];

  int tid  = threadIdx.x;
  int lane = tid & 63;
  int wave = tid >> 6;
  int wm   = (wave >> 1) * 64;
  int wn   = (wave & 1) * 64;
  int lr   = lane & 15;
  int quad = lane >> 4;

  if constexpr (EPI == 1) {
    if (tid < 128) {
      int t = slot_token[(size_t)e * M + m0 + tid];
      s_tok[tid]  = t;
      s_gate[tid] = (t >= 0) ? gate_buf[t] : 0.f;
    }
  }

  floatx4 acc[4][4];
#pragma unroll
  for (int i = 0; i < 4; i++)
#pragma unroll
    for (int j = 0; j < 4; j++) acc[i][j] = (floatx4){0.f, 0.f, 0.f, 0.f};

  // Staging geometry: wave w stages rows [w*32, w*32+32) of each tile in two
  // global_load_lds_dwordx4 (16 rows x 64 B each); lane i -> row +(i>>2),
  // k-chunk (i&3)*8.
  int rA0 = wave * 32 + (lane >> 2);
  int kcc = (lane & 3) * 8;
  const unsigned short* Ag0 = Ae + (size_t)(m0 + rA0)      * K + kcc;
  const unsigned short* Ag1 = Ae + (size_t)(m0 + rA0 + 16) * K + kcc;
  const unsigned short* Bg0 = Be + (size_t)(n0 + rA0)      * K + kcc;
  const unsigned short* Bg1 = Be + (size_t)(n0 + rA0 + 16) * K + kcc;
  const unsigned offA0 = (wave * 32) * 32;
  const unsigned offA1 = (wave * 32 + 16) * 32;

  // Prologue: stage 0 -> buf 0.
  gload_lds16(Ag0, &As[0][offA0]);
  gload_lds16(Ag1, &As[0][offA1]);
  gload_lds16(Bg0, &Bs[0][offA0]);
  gload_lds16(Bg1, &Bs[0][offA1]);
  Ag0 += 32; Ag1 += 32; Bg0 += 32; Bg1 += 32;

  int nIter = K >> 5;
  int buf = 0;
  for (int it = 0; it < nIter; ++it) {
    __syncthreads();   // vmcnt drain: As/Bs[buf] ready
    if (it + 1 < nIter) {
      gload_lds16(Ag0, &As[buf ^ 1][offA0]);
      gload_lds16(Ag1, &As[buf ^ 1][offA1]);
      gload_lds16(Bg0, &Bs[buf ^ 1][offA0]);
      gload_lds16(Bg1, &Bs[buf ^ 1][offA1]);
      Ag0 += 32; Ag1 += 32; Bg0 += 32; Bg1 += 32;
    }
    short8 af[4], bf[4];
#pragma unroll
    for (int i = 0; i < 4; i++) {
      af[i] = *(const short8*)(&As[buf][(wm + i * 16 + lr) * 32 + quad * 8]);
      bf[i] = *(const short8*)(&Bs[buf][(wn + i * 16 + lr) * 32 + quad * 8]);
    }
#pragma unroll
    for (int i = 0; i < 4; i++)
#pragma unroll
      for (int j = 0; j < 4; j++)
        acc[i][j] = __builtin_amdgcn_mfma_f32_16x16x32_bf16(af[i], bf[j], acc[i][j], 0, 0, 0);
    buf ^= 1;
  }

  // Epilogue. C/D layout: col = lane&15, row = quad*4 + reg (m89-verified).
#pragma unroll
  for (int i = 0; i < 4; i++) {
    int rloc = wm + i * 16 + quad * 4;
#pragma unroll
    for (int j = 0; j < 4; j++) {
      int col = n0 + wn + j * 16 + lr;
      float bz = bias[(size_t)e * Nn + col];
      if constexpr (EPI == 0) {
        size_t base = (size_t)e * M * Nn + (size_t)(m0 + rloc) * Nn + col;
#pragma unroll
        for (int r = 0; r < 4; r++)
          Hout[base + (size_t)r * Nn] = f2bf(gelu_fast(acc[i][j][r] + bz));
      } else {
#pragma unroll
        for (int r = 0; r < 4; r++) {
          int t = s_tok[rloc + r];
          if (t >= 0)
            Out[(size_t)t * D_ + col] = s_gate[rloc + r] * (acc[i][j][r] + bz);
        }
      }
    }
  }
}

// ---------------------------------------------------------------------------
extern "C" void kernel_launch(void* const* d_in, const int* in_sizes, int n_in,
                              void* d_out, int out_size, void* d_ws, size_t ws_size,
                              hipStream_t stream)
{
  (void)in_sizes; (void)n_in; (void)ws_size;
  const float* x  = (const float*)d_in[0];
  const float* wr = (const float*)d_in[1];
  const float* w1 = (const float*)d_in[2];
  const float* b1 = (const float*)d_in[3];
  const float* w2 = (const float*)d_in[4];
  const float* b2 = (const float*)d_in[5];
  float* out = (float*)d_out;

  // ws layout (~172 MB total)
  char* ws = (char*)d_ws;
  int*   idx_buf  = (int*)(ws + 0);              // 32 KB
  float* gate_buf = (float*)(ws + 32768);        // 32 KB
  float* stats    = (float*)(ws + 65536);        // 1 KB
  int*   slot_tok = (int*)(ws + 66560);          // 40 KB
  unsigned short* xe  = (unsigned short*)(ws + 107520);    // 20.97 MB
  unsigned short* wbf = (unsigned short*)(ws + 21079040);  // 67.1 MB (w1 then w2)
  unsigned short* hbf = (unsigned short*)(ws + 88187904);  // 83.9 MB; end 172073984

  hipMemsetAsync(d_out, 0, (size_t)out_size * 4, stream);       // dropped tokens -> 0
  hipMemsetAsync(stats, 0, 1024, stream);
  hipMemsetAsync(slot_tok, 0xFF, (size_t)E_ * B_ * C_ * 4, stream);  // -1 = empty slot

  router_kernel<<<(B_ * N_) / 4, 256, 0, stream>>>(x, wr, idx_buf, gate_buf, stats);
  pos_kernel<<<B_ * E_, 64, 0, stream>>>(idx_buf, slot_tok, stats,
                                         out + (size_t)B_ * N_ * D_);
  gather_kernel<<<E_ * M_, 256, 0, stream>>>(x, slot_tok, xe);

  // w1 [E][D][H] -> wbf [E][H][D]
  transcast_kernel<<<dim3(H_ / 64, D_ / 64, E_), 256, 0, stream>>>(w1, wbf, D_, H_);
  // h = gelu(xe @ w1 + b1): M=1280, K=1024, Nn=4096; grid = E * (32n x 10m)
  gemm_kernel<0><<<E_ * (H_ / 128) * (M_ / 128), 256, 0, stream>>>(
      xe, wbf, b1, hbf, nullptr, nullptr, nullptr, M_, D_, H_, M_ / 128);
  // w2 [E][H][D] -> wbf [E][D][H]  (reuse buffer; stream-serialized after GEMM1)
  transcast_kernel<<<dim3(D_ / 64, H_ / 64, E_), 256, 0, stream>>>(w2, wbf, H_, D_);
  // out = gate * (h @ w2 + b2): M=1280, K=4096, Nn=1024; grid = E * (8n x 10m)
  gemm_kernel<1><<<E_ * (D_ / 128) * (M_ / 128), 256, 0, stream>>>(
      hbf, wbf, b2, nullptr, out, slot_tok, gate_buf, M_, H_, D_, M_ / 128);
}